// Round 5
// baseline (213.154 us; speedup 1.0000x reference)
//
#include <hip/hip_runtime.h>
#include <hip/hip_bf16.h>

#define Bsz 4
#define Ssz 2048
#define Dsz 512
#define Hsz 8
#define DKsz 64

typedef __bf16 bf16x8 __attribute__((ext_vector_type(8)));
typedef __bf16 bf16x4 __attribute__((ext_vector_type(4)));
typedef float f32x4 __attribute__((ext_vector_type(4)));

// chunk-swizzled element offset: 16B chunk c of a 64-elem (128B) row, XOR row&7
#define SWE(c, row) ((((c) ^ ((row) & 7)) * 8))

// ---------------------------------------------------------------------------
// cvt: x (4.19M fp32) + Wq|Wk|Wv (3 x 262144 fp32) -> bf16 in ws.
__global__ __launch_bounds__(256) void cvt_kernel(
    const float* __restrict__ x, const float* __restrict__ Wq,
    const float* __restrict__ Wk, const float* __restrict__ Wv,
    __bf16* __restrict__ xb, __bf16* __restrict__ Wb)
{
    const int i = blockIdx.x * 256 + threadIdx.x;   // float4 index
    const int XN4 = (Bsz * Ssz * Dsz) / 4;          // 1,048,576
    const float* src;
    __bf16* dst;
    int off;
    if (i < XN4) {
        src = x; dst = xb; off = i;
    } else {
        int j = i - XN4;                             // 0 .. 196607
        int w = j >> 16;                             // 0,1,2
        off = j & 65535;
        src = (w == 0) ? Wq : (w == 1) ? Wk : Wv;
        dst = Wb + (size_t)w * (Dsz * Dsz);
    }
    float4 v = ((const float4*)src)[off];
    __bf16 o[4] = {(__bf16)v.x, (__bf16)v.y, (__bf16)v.z, (__bf16)v.w};
    *(uint2*)(dst + (size_t)off * 4) = *(uint2*)o;
}

// ---------------------------------------------------------------------------
// Fused qkv projection: one kernel, blockIdx.z selects Q/K/V (768 blocks ->
// 3 blocks/CU). 128x128 tile, swizzled LDS, reg prefetch, packed 8B stores.
// which<2 (Q/K): C = W-tile x x-tile -> rows=e (in-lane), cols=s.
// which==2 (V) : C = x-tile x W-tile -> rows=s (in-lane), cols=e -> V^T.
__global__ __launch_bounds__(256, 3) void qkv_kernel(
    const __bf16* __restrict__ xb, const __bf16* __restrict__ Wb,
    __bf16* __restrict__ Qo, __bf16* __restrict__ Ko, __bf16* __restrict__ Vo)
{
    __shared__ __bf16 xs[128][64];
    __shared__ __bf16 wsh[128][64];

    const int tid  = threadIdx.x;
    const int lane = tid & 63;
    const int wave = tid >> 6;
    const int quad = lane >> 4;
    const int l16  = lane & 15;
    const int wm   = (wave & 1) * 64;
    const int wn   = (wave >> 1) * 64;

    const int tm = blockIdx.x * 128;      // x-row tile
    const int tn = blockIdx.y * 128;      // W-row tile
    const int which = blockIdx.z;         // 0=Q 1=K 2=V
    const bool VM = (which == 2);
    const __bf16* W = Wb + (size_t)which * (Dsz * Dsz);

    const int srow = tid >> 1;            // 0..127
    const int c0   = (tid & 1) * 4;       // chunks c0..c0+3

    const __bf16* xg = xb + (size_t)(tm + srow) * Dsz;
    const __bf16* wg = W  + (size_t)(tn + srow) * Dsz;

    bf16x8 px[4], pw[4];
    #pragma unroll
    for (int i = 0; i < 4; ++i) {
        px[i] = *(const bf16x8*)(xg + (c0 + i) * 8);
        pw[i] = *(const bf16x8*)(wg + (c0 + i) * 8);
    }

    f32x4 acc[4][4];
    #pragma unroll
    for (int i = 0; i < 4; ++i)
        #pragma unroll
        for (int j = 0; j < 4; ++j) acc[i][j] = (f32x4){0.f, 0.f, 0.f, 0.f};

    const __bf16 (*Ash)[64] = VM ? xs : wsh;
    const __bf16 (*Bsh)[64] = VM ? wsh : xs;

    for (int k0 = 0; k0 < Dsz; k0 += 64) {
        __syncthreads();
        #pragma unroll
        for (int i = 0; i < 4; ++i) {
            *(bf16x8*)&xs[srow][SWE(c0 + i, srow)]  = px[i];
            *(bf16x8*)&wsh[srow][SWE(c0 + i, srow)] = pw[i];
        }
        __syncthreads();
        if (k0 + 64 < Dsz) {
            #pragma unroll
            for (int i = 0; i < 4; ++i) {
                px[i] = *(const bf16x8*)(xg + k0 + 64 + (c0 + i) * 8);
                pw[i] = *(const bf16x8*)(wg + k0 + 64 + (c0 + i) * 8);
            }
        }

        #pragma unroll
        for (int kk = 0; kk < 2; ++kk) {
            bf16x8 fa[4], fb[4];
            #pragma unroll
            for (int mi = 0; mi < 4; ++mi) {
                const int row = wm + mi * 16 + l16;
                fa[mi] = *(const bf16x8*)&Ash[row][SWE(kk * 4 + quad, row)];
            }
            #pragma unroll
            for (int ni = 0; ni < 4; ++ni) {
                const int row = wn + ni * 16 + l16;
                fb[ni] = *(const bf16x8*)&Bsh[row][SWE(kk * 4 + quad, row)];
            }
            #pragma unroll
            for (int mi = 0; mi < 4; ++mi)
                #pragma unroll
                for (int ni = 0; ni < 4; ++ni)
                    acc[mi][ni] = __builtin_amdgcn_mfma_f32_16x16x32_bf16(
                        fa[mi], fb[ni], acc[mi][ni], 0, 0, 0);
        }
    }

    if (!VM) {
        const float scale = (which == 0) ? 0.125f * 1.44269504088896340736f : 1.0f;
        __bf16* dst = (which == 0) ? Qo : Ko;
        // rows = e (W-dim), in-lane regs r span 4 consecutive e -> 4 consecutive d
        #pragma unroll
        for (int mi = 0; mi < 4; ++mi) {
            const int e0 = tn + wm + mi * 16 + quad * 4;
            const int h = e0 >> 6, d0 = e0 & 63;
            #pragma unroll
            for (int ni = 0; ni < 4; ++ni) {
                const int sf = tm + wn + ni * 16 + l16;
                const int b = sf >> 11, s = sf & (Ssz - 1);
                bf16x4 p;
                #pragma unroll
                for (int r = 0; r < 4; ++r) p[r] = (__bf16)(acc[mi][ni][r] * scale);
                *(bf16x4*)&dst[((((size_t)(b * Hsz + h) * Ssz + s)) << 6) + d0] = p;
            }
        }
    } else {
        // rows = s, in-lane regs r span 4 consecutive s -> V^T packed stores
        #pragma unroll
        for (int mi = 0; mi < 4; ++mi) {
            const int sf0 = tm + wm + mi * 16 + quad * 4;
            const int b = sf0 >> 11, s0 = sf0 & (Ssz - 1);
            #pragma unroll
            for (int ni = 0; ni < 4; ++ni) {
                const int e = tn + wn + ni * 16 + l16;
                const int h = e >> 6, d = e & 63;
                bf16x4 p;
                #pragma unroll
                for (int r = 0; r < 4; ++r) p[r] = (__bf16)acc[mi][ni][r];
                *(bf16x4*)&Vo[(((size_t)(b * Hsz + h) * DKsz + d) << 11) + s0] = p;
            }
        }
    }
}

// ---------------------------------------------------------------------------
// Barrier-free flash attention. K/V per (b,h) is 512 KB and L2-resident
// (bh -> XCD swizzle via blockIdx.x), so MFMA fragments load DIRECTLY from
// global/L2 -- no LDS staging, no __syncthreads in the k-loop. Each wave owns
// 32 q-rows (qs=2); LDS only for the per-wave P transpose. Register prefetch
// of next k-tile's 16 b128 fragment loads hides L2 latency.
__global__ __launch_bounds__(256, 2) void attn_kernel(
    const __bf16* __restrict__ Q, const __bf16* __restrict__ K,
    const __bf16* __restrict__ VT, float* __restrict__ out)
{
    __shared__ __bf16 ps[4][2][16][64];  // wave, qs, P-row(q), col(s) swizzled

    const int tid  = threadIdx.x;
    const int lane = tid & 63;
    const int wave = tid >> 6;
    const int quad = lane >> 4;
    const int l16  = lane & 15;

    const int bh = blockIdx.x;           // all q-blocks of a bh share an XCD L2
    const int qt = blockIdx.y;           // 128-row q tile
    const int b  = bh >> 3;
    const int h  = bh & 7;

    const __bf16* Qb = Q  + (size_t)bh * Ssz * DKsz;
    const __bf16* Kb = K  + (size_t)bh * Ssz * DKsz;
    const __bf16* Vb = VT + (size_t)bh * DKsz * Ssz;

    // Q fragments: lane l16 = q-local row, quad*8 = dk chunk
    bf16x8 qf[2][2];
    #pragma unroll
    for (int qs = 0; qs < 2; ++qs) {
        const __bf16* qrow = Qb + (size_t)(qt * 128 + wave * 32 + qs * 16 + l16) * DKsz;
        qf[qs][0] = *(const bf16x8*)(qrow + quad * 8);
        qf[qs][1] = *(const bf16x8*)(qrow + 32 + quad * 8);
    }

    bf16x8 ones;
    #pragma unroll
    for (int i = 0; i < 8; ++i) ones[i] = (__bf16)1.0f;

    f32x4 oacc[2][4];
    #pragma unroll
    for (int qs = 0; qs < 2; ++qs)
        #pragma unroll
        for (int i = 0; i < 4; ++i) oacc[qs][i] = (f32x4){0.f, 0.f, 0.f, 0.f};
    f32x4 lacc[2] = {(f32x4){0.f, 0.f, 0.f, 0.f}, (f32x4){0.f, 0.f, 0.f, 0.f}};

    // K frag (B-op of QK^T): B[k=dk][n=s]: lane l16 = s-local, dk = kk*32+quad*8
    // V frag (A-op of O^T=V^T P^T): A[m=d][k=s]: lane l16 = d-local, s = kk*32+quad*8
    bf16x8 kc[2][4], vc[2][4], kn[2][4], vn[2][4];
    #pragma unroll
    for (int kk = 0; kk < 2; ++kk)
        #pragma unroll
        for (int ns = 0; ns < 4; ++ns) {
            kc[kk][ns] = *(const bf16x8*)(Kb + (size_t)(ns * 16 + l16) * DKsz + kk * 32 + quad * 8);
            vc[kk][ns] = *(const bf16x8*)(Vb + (size_t)(ns * 16 + l16) * Ssz + kk * 32 + quad * 8);
        }

    #pragma unroll 2
    for (int kb = 0; kb < Ssz; kb += 64) {
        if (kb + 64 < Ssz) {
            #pragma unroll
            for (int kk = 0; kk < 2; ++kk)
                #pragma unroll
                for (int ns = 0; ns < 4; ++ns) {
                    kn[kk][ns] = *(const bf16x8*)(Kb + (size_t)(kb + 64 + ns * 16 + l16) * DKsz + kk * 32 + quad * 8);
                    vn[kk][ns] = *(const bf16x8*)(Vb + (size_t)(ns * 16 + l16) * Ssz + kb + 64 + kk * 32 + quad * 8);
                }
        }

        #pragma unroll
        for (int qs = 0; qs < 2; ++qs) {
            // S = Q K^T (C: row=q-local=quad*4+r, col=s-local=ns*16+l16)
            f32x4 sacc[4];
            #pragma unroll
            for (int ns = 0; ns < 4; ++ns) {
                sacc[ns] = (f32x4){0.f, 0.f, 0.f, 0.f};
                sacc[ns] = __builtin_amdgcn_mfma_f32_16x16x32_bf16(qf[qs][0], kc[0][ns], sacc[ns], 0, 0, 0);
                sacc[ns] = __builtin_amdgcn_mfma_f32_16x16x32_bf16(qf[qs][1], kc[1][ns], sacc[ns], 0, 0, 0);
            }
            // P = exp2(S) -> per-wave LDS (C-layout -> B-frag layout)
            #pragma unroll
            for (int ns = 0; ns < 4; ++ns) {
                const int c = ns * 2 + (l16 >> 3);
                #pragma unroll
                for (int r = 0; r < 4; ++r) {
                    const int prow = quad * 4 + r;
                    ps[wave][qs][prow][SWE(c, prow) + (l16 & 7)] =
                        (__bf16)__builtin_amdgcn_exp2f(sacc[ns][r]);
                }
            }
            bf16x8 af0 = *(const bf16x8*)&ps[wave][qs][l16][SWE(quad, l16)];
            bf16x8 af1 = *(const bf16x8*)&ps[wave][qs][l16][SWE(4 + quad, l16)];
            // O^T += V^T P^T : rows=d (in-lane regs), cols=q (l16)
            #pragma unroll
            for (int ns = 0; ns < 4; ++ns) {
                oacc[qs][ns] = __builtin_amdgcn_mfma_f32_16x16x32_bf16(vc[0][ns], af0, oacc[qs][ns], 0, 0, 0);
                oacc[qs][ns] = __builtin_amdgcn_mfma_f32_16x16x32_bf16(vc[1][ns], af1, oacc[qs][ns], 0, 0, 0);
            }
            lacc[qs] = __builtin_amdgcn_mfma_f32_16x16x32_bf16(ones, af0, lacc[qs], 0, 0, 0);
            lacc[qs] = __builtin_amdgcn_mfma_f32_16x16x32_bf16(ones, af1, lacc[qs], 0, 0, 0);
        }

        #pragma unroll
        for (int kk = 0; kk < 2; ++kk)
            #pragma unroll
            for (int ns = 0; ns < 4; ++ns) {
                kc[kk][ns] = kn[kk][ns];
                vc[kk][ns] = vn[kk][ns];
            }
    }

    // epilogue: per-lane row-sum (col=q=l16), f32x4 stores along d
    #pragma unroll
    for (int qs = 0; qs < 2; ++qs) {
        const float linv = 1.f / (lacc[qs][0] + 1e-8f);
        const int q = qt * 128 + wave * 32 + qs * 16 + l16;
        float* obase = out + ((size_t)b * Ssz + q) * Dsz + h * DKsz;
        #pragma unroll
        for (int ns = 0; ns < 4; ++ns) {
            f32x4 o = oacc[qs][ns] * linv;
            *(f32x4*)(obase + ns * 16 + quad * 4) = o;
        }
    }
}

extern "C" void kernel_launch(void* const* d_in, const int* in_sizes, int n_in,
                              void* d_out, int out_size, void* d_ws, size_t ws_size,
                              hipStream_t stream) {
    const float* x  = (const float*)d_in[0];
    const float* Wq = (const float*)d_in[1];
    const float* Wk = (const float*)d_in[2];
    const float* Wv = (const float*)d_in[3];
    float* out = (float*)d_out;

    const size_t per = (size_t)Bsz * Hsz * Ssz * DKsz;  // 4,194,304 elems
    __bf16* Qw  = (__bf16*)d_ws;
    __bf16* Kw  = Qw + per;
    __bf16* VTw = Kw + per;
    __bf16* xb  = VTw + per;
    __bf16* Wb  = xb + per;                              // 786,432 elems

    cvt_kernel<<<4864, 256, 0, stream>>>(x, Wq, Wk, Wv, xb, Wb);
    qkv_kernel<<<dim3((Bsz * Ssz) / 128, Dsz / 128, 3), 256, 0, stream>>>(
        xb, Wb, Qw, Kw, VTw);
    attn_kernel<<<dim3(Bsz * Hsz, Ssz / 128), 256, 0, stream>>>(Qw, Kw, VTw, out);
}

// Round 6
// 147.640 us; speedup vs baseline: 1.4437x; 1.4437x over previous
//
#include <hip/hip_runtime.h>
#include <hip/hip_bf16.h>

#define Bsz 4
#define Ssz 2048
#define Dsz 512
#define Hsz 8
#define DKsz 64

typedef __bf16 bf16x8 __attribute__((ext_vector_type(8)));
typedef __bf16 bf16x4 __attribute__((ext_vector_type(4)));
typedef float f32x4 __attribute__((ext_vector_type(4)));

// chunk-swizzled element offset: 16B chunk c of a 64-elem (128B) row, XOR row&7
#define SWE(c, row) ((((c) ^ ((row) & 7)) * 8))

// ---------------------------------------------------------------------------
// cvt: x (4.19M fp32) + Wq|Wk|Wv (3 x 262144 fp32) -> bf16 in ws.
__global__ __launch_bounds__(256) void cvt_kernel(
    const float* __restrict__ x, const float* __restrict__ Wq,
    const float* __restrict__ Wk, const float* __restrict__ Wv,
    __bf16* __restrict__ xb, __bf16* __restrict__ Wb)
{
    const int i = blockIdx.x * 256 + threadIdx.x;   // float4 index
    const int XN4 = (Bsz * Ssz * Dsz) / 4;          // 1,048,576
    const float* src;
    __bf16* dst;
    int off;
    if (i < XN4) {
        src = x; dst = xb; off = i;
    } else {
        int j = i - XN4;                             // 0 .. 196607
        int w = j >> 16;                             // 0,1,2
        off = j & 65535;
        src = (w == 0) ? Wq : (w == 1) ? Wk : Wv;
        dst = Wb + (size_t)w * (Dsz * Dsz);
    }
    float4 v = ((const float4*)src)[off];
    __bf16 o[4] = {(__bf16)v.x, (__bf16)v.y, (__bf16)v.z, (__bf16)v.w};
    *(uint2*)(dst + (size_t)off * 4) = *(uint2*)o;
}

// ---------------------------------------------------------------------------
// Fused qkv projection: one kernel, blockIdx.z selects Q/K/V (768 blocks ->
// 3 blocks/CU). 128x128 tile, swizzled LDS, reg prefetch, packed 8B stores.
// which<2 (Q/K): C = W-tile x x-tile -> rows=e (in-lane), cols=s.
// which==2 (V) : C = x-tile x W-tile -> rows=s (in-lane), cols=e -> V^T.
__global__ __launch_bounds__(256, 2) void qkv_kernel(
    const __bf16* __restrict__ xb, const __bf16* __restrict__ Wb,
    __bf16* __restrict__ Qo, __bf16* __restrict__ Ko, __bf16* __restrict__ Vo)
{
    __shared__ __bf16 xs[128][64];
    __shared__ __bf16 wsh[128][64];

    const int tid  = threadIdx.x;
    const int lane = tid & 63;
    const int wave = tid >> 6;
    const int quad = lane >> 4;
    const int l16  = lane & 15;
    const int wm   = (wave & 1) * 64;
    const int wn   = (wave >> 1) * 64;

    const int tm = blockIdx.x * 128;      // x-row tile
    const int tn = blockIdx.y * 128;      // W-row tile
    const int which = blockIdx.z;         // 0=Q 1=K 2=V
    const bool VM = (which == 2);
    const __bf16* W = Wb + (size_t)which * (Dsz * Dsz);

    const int srow = tid >> 1;            // 0..127
    const int c0   = (tid & 1) * 4;       // chunks c0..c0+3

    const __bf16* xg = xb + (size_t)(tm + srow) * Dsz;
    const __bf16* wg = W  + (size_t)(tn + srow) * Dsz;

    bf16x8 px[4], pw[4];
    #pragma unroll
    for (int i = 0; i < 4; ++i) {
        px[i] = *(const bf16x8*)(xg + (c0 + i) * 8);
        pw[i] = *(const bf16x8*)(wg + (c0 + i) * 8);
    }

    f32x4 acc[4][4];
    #pragma unroll
    for (int i = 0; i < 4; ++i)
        #pragma unroll
        for (int j = 0; j < 4; ++j) acc[i][j] = (f32x4){0.f, 0.f, 0.f, 0.f};

    const __bf16 (*Ash)[64] = VM ? xs : wsh;
    const __bf16 (*Bsh)[64] = VM ? wsh : xs;

    for (int k0 = 0; k0 < Dsz; k0 += 64) {
        __syncthreads();
        #pragma unroll
        for (int i = 0; i < 4; ++i) {
            *(bf16x8*)&xs[srow][SWE(c0 + i, srow)]  = px[i];
            *(bf16x8*)&wsh[srow][SWE(c0 + i, srow)] = pw[i];
        }
        __syncthreads();
        if (k0 + 64 < Dsz) {
            #pragma unroll
            for (int i = 0; i < 4; ++i) {
                px[i] = *(const bf16x8*)(xg + k0 + 64 + (c0 + i) * 8);
                pw[i] = *(const bf16x8*)(wg + k0 + 64 + (c0 + i) * 8);
            }
        }

        #pragma unroll
        for (int kk = 0; kk < 2; ++kk) {
            bf16x8 fa[4], fb[4];
            #pragma unroll
            for (int mi = 0; mi < 4; ++mi) {
                const int row = wm + mi * 16 + l16;
                fa[mi] = *(const bf16x8*)&Ash[row][SWE(kk * 4 + quad, row)];
            }
            #pragma unroll
            for (int ni = 0; ni < 4; ++ni) {
                const int row = wn + ni * 16 + l16;
                fb[ni] = *(const bf16x8*)&Bsh[row][SWE(kk * 4 + quad, row)];
            }
            #pragma unroll
            for (int mi = 0; mi < 4; ++mi)
                #pragma unroll
                for (int ni = 0; ni < 4; ++ni)
                    acc[mi][ni] = __builtin_amdgcn_mfma_f32_16x16x32_bf16(
                        fa[mi], fb[ni], acc[mi][ni], 0, 0, 0);
        }
    }

    if (!VM) {
        const float scale = (which == 0) ? 0.125f * 1.44269504088896340736f : 1.0f;
        __bf16* dst = (which == 0) ? Qo : Ko;
        // rows = e (W-dim), in-lane regs r span 4 consecutive e -> 4 consecutive d
        #pragma unroll
        for (int mi = 0; mi < 4; ++mi) {
            const int e0 = tn + wm + mi * 16 + quad * 4;
            const int h = e0 >> 6, d0 = e0 & 63;
            #pragma unroll
            for (int ni = 0; ni < 4; ++ni) {
                const int sf = tm + wn + ni * 16 + l16;
                const int b = sf >> 11, s = sf & (Ssz - 1);
                bf16x4 p;
                #pragma unroll
                for (int r = 0; r < 4; ++r) p[r] = (__bf16)(acc[mi][ni][r] * scale);
                *(bf16x4*)&dst[((((size_t)(b * Hsz + h) * Ssz + s)) << 6) + d0] = p;
            }
        }
    } else {
        // rows = s, in-lane regs r span 4 consecutive s -> V^T packed stores
        #pragma unroll
        for (int mi = 0; mi < 4; ++mi) {
            const int sf0 = tm + wm + mi * 16 + quad * 4;
            const int b = sf0 >> 11, s0 = sf0 & (Ssz - 1);
            #pragma unroll
            for (int ni = 0; ni < 4; ++ni) {
                const int e = tn + wn + ni * 16 + l16;
                const int h = e >> 6, d = e & 63;
                bf16x4 p;
                #pragma unroll
                for (int r = 0; r < 4; ++r) p[r] = (__bf16)acc[mi][ni][r];
                *(bf16x4*)&Vo[(((size_t)(b * Hsz + h) * DKsz + d) << 11) + s0] = p;
            }
        }
    }
}

// ---------------------------------------------------------------------------
// Flash attention, LDS-staged K/V (shared across the 4 waves), XOR-swizzled
// (conflict-free b128), 128 q-rows/block (512 blocks = 2/CU), qs=2 per wave.
// Swapped-operand PV => O^T in regs -> f32x4 stores; per-lane MFMA row-sums.
// Register prefetch of next K/V staging tile hides HBM/L2 latency.
__global__ __launch_bounds__(256, 2) void attn_kernel(
    const __bf16* __restrict__ Q, const __bf16* __restrict__ K,
    const __bf16* __restrict__ VT, float* __restrict__ out)
{
    __shared__ __bf16 ks[64][64];        // K[s_local][dk], swizzled chunks
    __shared__ __bf16 vs[64][64];        // V^T[dk][s_local], swizzled chunks
    __shared__ __bf16 ps[4][16][64];     // per-wave P buffer (reused per qs)

    const int tid  = threadIdx.x;
    const int lane = tid & 63;
    const int wave = tid >> 6;
    const int quad = lane >> 4;
    const int l16  = lane & 15;

    const int bh = blockIdx.x;           // all q-blocks of a bh share an XCD L2
    const int qt = blockIdx.y;           // 128-row q tile
    const int b  = bh >> 3;
    const int h  = bh & 7;

    const __bf16* Qb = Q  + (size_t)bh * Ssz * DKsz;
    const __bf16* Kb = K  + (size_t)bh * Ssz * DKsz;
    const __bf16* Vb = VT + (size_t)bh * DKsz * Ssz;

    // Q fragments: lane l16 = q-local row, quad*8 = dk chunk
    bf16x8 qf[2][2];
    #pragma unroll
    for (int qs = 0; qs < 2; ++qs) {
        const __bf16* qrow = Qb + (size_t)(qt * 128 + wave * 32 + qs * 16 + l16) * DKsz;
        qf[qs][0] = *(const bf16x8*)(qrow + quad * 8);
        qf[qs][1] = *(const bf16x8*)(qrow + 32 + quad * 8);
    }

    bf16x8 ones;
    #pragma unroll
    for (int i = 0; i < 8; ++i) ones[i] = (__bf16)1.0f;

    f32x4 oacc[2][4];
    #pragma unroll
    for (int qs = 0; qs < 2; ++qs)
        #pragma unroll
        for (int i = 0; i < 4; ++i) oacc[qs][i] = (f32x4){0.f, 0.f, 0.f, 0.f};
    f32x4 lacc[2] = {(f32x4){0.f, 0.f, 0.f, 0.f}, (f32x4){0.f, 0.f, 0.f, 0.f}};

    const int srow = tid >> 2;           // 0..63
    const int c0   = tid & 3;            // chunks c0, c0+4

    bf16x8 pk0 = *(const bf16x8*)(Kb + (size_t)srow * DKsz + c0 * 8);
    bf16x8 pk1 = *(const bf16x8*)(Kb + (size_t)srow * DKsz + (c0 + 4) * 8);
    bf16x8 pv0 = *(const bf16x8*)(Vb + (size_t)srow * Ssz + c0 * 8);
    bf16x8 pv1 = *(const bf16x8*)(Vb + (size_t)srow * Ssz + (c0 + 4) * 8);

    for (int kb = 0; kb < Ssz; kb += 64) {
        __syncthreads();                 // previous tile fully consumed
        *(bf16x8*)&ks[srow][SWE(c0, srow)]     = pk0;
        *(bf16x8*)&ks[srow][SWE(c0 + 4, srow)] = pk1;
        *(bf16x8*)&vs[srow][SWE(c0, srow)]     = pv0;
        *(bf16x8*)&vs[srow][SWE(c0 + 4, srow)] = pv1;
        __syncthreads();

        if (kb + 64 < Ssz) {             // prefetch next K/V tile into regs
            pk0 = *(const bf16x8*)(Kb + (size_t)(kb + 64 + srow) * DKsz + c0 * 8);
            pk1 = *(const bf16x8*)(Kb + (size_t)(kb + 64 + srow) * DKsz + (c0 + 4) * 8);
            pv0 = *(const bf16x8*)(Vb + (size_t)srow * Ssz + kb + 64 + c0 * 8);
            pv1 = *(const bf16x8*)(Vb + (size_t)srow * Ssz + kb + 64 + (c0 + 4) * 8);
        }

        // read K and V tiles from LDS once into registers
        bf16x8 kf[2][4], vf[2][4];
        #pragma unroll
        for (int kk = 0; kk < 2; ++kk)
            #pragma unroll
            for (int ns = 0; ns < 4; ++ns) {
                const int row = ns * 16 + l16;
                kf[kk][ns] = *(const bf16x8*)&ks[row][SWE(kk * 4 + quad, row)];
                vf[kk][ns] = *(const bf16x8*)&vs[row][SWE(kk * 4 + quad, row)];
            }

        #pragma unroll
        for (int qs = 0; qs < 2; ++qs) {
            // S = Q K^T (C: row=q-local=quad*4+r, col=s-local=ns*16+l16)
            f32x4 sacc[4];
            #pragma unroll
            for (int ns = 0; ns < 4; ++ns) {
                sacc[ns] = (f32x4){0.f, 0.f, 0.f, 0.f};
                sacc[ns] = __builtin_amdgcn_mfma_f32_16x16x32_bf16(qf[qs][0], kf[0][ns], sacc[ns], 0, 0, 0);
                sacc[ns] = __builtin_amdgcn_mfma_f32_16x16x32_bf16(qf[qs][1], kf[1][ns], sacc[ns], 0, 0, 0);
            }
            // P = exp2(S) -> per-wave LDS (C-layout -> B-frag layout); in-wave
            // RAW/WAR ordering via lgkmcnt, no barrier needed (per-wave buffer)
            #pragma unroll
            for (int ns = 0; ns < 4; ++ns) {
                const int c = ns * 2 + (l16 >> 3);
                #pragma unroll
                for (int r = 0; r < 4; ++r) {
                    const int prow = quad * 4 + r;
                    ps[wave][prow][SWE(c, prow) + (l16 & 7)] =
                        (__bf16)__builtin_amdgcn_exp2f(sacc[ns][r]);
                }
            }
            bf16x8 af0 = *(const bf16x8*)&ps[wave][l16][SWE(quad, l16)];
            bf16x8 af1 = *(const bf16x8*)&ps[wave][l16][SWE(4 + quad, l16)];
            // O^T += V^T P^T : rows=d (in-lane regs), cols=q (l16)
            #pragma unroll
            for (int ns = 0; ns < 4; ++ns) {
                oacc[qs][ns] = __builtin_amdgcn_mfma_f32_16x16x32_bf16(vf[0][ns], af0, oacc[qs][ns], 0, 0, 0);
                oacc[qs][ns] = __builtin_amdgcn_mfma_f32_16x16x32_bf16(vf[1][ns], af1, oacc[qs][ns], 0, 0, 0);
            }
            lacc[qs] = __builtin_amdgcn_mfma_f32_16x16x32_bf16(ones, af0, lacc[qs], 0, 0, 0);
            lacc[qs] = __builtin_amdgcn_mfma_f32_16x16x32_bf16(ones, af1, lacc[qs], 0, 0, 0);
        }
    }

    // epilogue: per-lane row-sum (col=q=l16), f32x4 stores along d
    #pragma unroll
    for (int qs = 0; qs < 2; ++qs) {
        const float linv = 1.f / (lacc[qs][0] + 1e-8f);
        const int q = qt * 128 + wave * 32 + qs * 16 + l16;
        float* obase = out + ((size_t)b * Ssz + q) * Dsz + h * DKsz;
        #pragma unroll
        for (int ns = 0; ns < 4; ++ns) {
            f32x4 o = oacc[qs][ns] * linv;
            *(f32x4*)(obase + ns * 16 + quad * 4) = o;
        }
    }
}

extern "C" void kernel_launch(void* const* d_in, const int* in_sizes, int n_in,
                              void* d_out, int out_size, void* d_ws, size_t ws_size,
                              hipStream_t stream) {
    const float* x  = (const float*)d_in[0];
    const float* Wq = (const float*)d_in[1];
    const float* Wk = (const float*)d_in[2];
    const float* Wv = (const float*)d_in[3];
    float* out = (float*)d_out;

    const size_t per = (size_t)Bsz * Hsz * Ssz * DKsz;  // 4,194,304 elems
    __bf16* Qw  = (__bf16*)d_ws;
    __bf16* Kw  = Qw + per;
    __bf16* VTw = Kw + per;
    __bf16* xb  = VTw + per;
    __bf16* Wb  = xb + per;                              // 786,432 elems

    cvt_kernel<<<4864, 256, 0, stream>>>(x, Wq, Wk, Wv, xb, Wb);
    qkv_kernel<<<dim3((Bsz * Ssz) / 128, Dsz / 128, 3), 256, 0, stream>>>(
        xb, Wb, Qw, Kw, VTw);
    attn_kernel<<<dim3(Bsz * Hsz, Ssz / 128), 256, 0, stream>>>(Qw, Kw, VTw, out);
}

// Round 7
// 139.583 us; speedup vs baseline: 1.5271x; 1.0577x over previous
//
#include <hip/hip_runtime.h>
#include <hip/hip_bf16.h>

#define Bsz 4
#define Ssz 2048
#define Dsz 512
#define Hsz 8
#define DKsz 64

typedef __bf16 bf16x8 __attribute__((ext_vector_type(8)));
typedef __bf16 bf16x4 __attribute__((ext_vector_type(4)));
typedef float f32x4 __attribute__((ext_vector_type(4)));

// chunk-swizzled element offset: 16B chunk c of a 64-elem (128B) row, XOR row&7
#define SWE(c, row) ((((c) ^ ((row) & 7)) * 8))

// ---------------------------------------------------------------------------
// cvt: x (4.19M fp32) + Wq|Wk|Wv (3 x 262144 fp32) -> bf16 in ws.
__global__ __launch_bounds__(256) void cvt_kernel(
    const float* __restrict__ x, const float* __restrict__ Wq,
    const float* __restrict__ Wk, const float* __restrict__ Wv,
    __bf16* __restrict__ xb, __bf16* __restrict__ Wb)
{
    const int i = blockIdx.x * 256 + threadIdx.x;   // float4 index
    const int XN4 = (Bsz * Ssz * Dsz) / 4;          // 1,048,576
    const float* src;
    __bf16* dst;
    int off;
    if (i < XN4) {
        src = x; dst = xb; off = i;
    } else {
        int j = i - XN4;                             // 0 .. 196607
        int w = j >> 16;                             // 0,1,2
        off = j & 65535;
        src = (w == 0) ? Wq : (w == 1) ? Wk : Wv;
        dst = Wb + (size_t)w * (Dsz * Dsz);
    }
    float4 v = ((const float4*)src)[off];
    __bf16 o[4] = {(__bf16)v.x, (__bf16)v.y, (__bf16)v.z, (__bf16)v.w};
    *(uint2*)(dst + (size_t)off * 4) = *(uint2*)o;
}

// ---------------------------------------------------------------------------
// Fused qkv projection: one kernel, blockIdx.z selects Q/K/V. 128x128 tile,
// swizzled LDS, reg prefetch, packed 8B stores. occupancy 3 blocks/CU.
// which<2 (Q/K): C = W-tile x x-tile -> rows=e (in-lane), cols=s.
// which==2 (V) : C = x-tile x W-tile -> rows=s (in-lane), cols=e -> V^T.
__global__ __launch_bounds__(256, 3) void qkv_kernel(
    const __bf16* __restrict__ xb, const __bf16* __restrict__ Wb,
    __bf16* __restrict__ Qo, __bf16* __restrict__ Ko, __bf16* __restrict__ Vo)
{
    __shared__ __bf16 xs[128][64];
    __shared__ __bf16 wsh[128][64];

    const int tid  = threadIdx.x;
    const int lane = tid & 63;
    const int wave = tid >> 6;
    const int quad = lane >> 4;
    const int l16  = lane & 15;
    const int wm   = (wave & 1) * 64;
    const int wn   = (wave >> 1) * 64;

    const int tm = blockIdx.x * 128;      // x-row tile
    const int tn = blockIdx.y * 128;      // W-row tile
    const int which = blockIdx.z;         // 0=Q 1=K 2=V
    const bool VM = (which == 2);
    const __bf16* W = Wb + (size_t)which * (Dsz * Dsz);

    const int srow = tid >> 1;            // 0..127
    const int c0   = (tid & 1) * 4;       // chunks c0..c0+3

    const __bf16* xg = xb + (size_t)(tm + srow) * Dsz;
    const __bf16* wg = W  + (size_t)(tn + srow) * Dsz;

    bf16x8 px[4], pw[4];
    #pragma unroll
    for (int i = 0; i < 4; ++i) {
        px[i] = *(const bf16x8*)(xg + (c0 + i) * 8);
        pw[i] = *(const bf16x8*)(wg + (c0 + i) * 8);
    }

    f32x4 acc[4][4];
    #pragma unroll
    for (int i = 0; i < 4; ++i)
        #pragma unroll
        for (int j = 0; j < 4; ++j) acc[i][j] = (f32x4){0.f, 0.f, 0.f, 0.f};

    const __bf16 (*Ash)[64] = VM ? xs : wsh;
    const __bf16 (*Bsh)[64] = VM ? wsh : xs;

    for (int k0 = 0; k0 < Dsz; k0 += 64) {
        __syncthreads();
        #pragma unroll
        for (int i = 0; i < 4; ++i) {
            *(bf16x8*)&xs[srow][SWE(c0 + i, srow)]  = px[i];
            *(bf16x8*)&wsh[srow][SWE(c0 + i, srow)] = pw[i];
        }
        __syncthreads();
        if (k0 + 64 < Dsz) {
            #pragma unroll
            for (int i = 0; i < 4; ++i) {
                px[i] = *(const bf16x8*)(xg + k0 + 64 + (c0 + i) * 8);
                pw[i] = *(const bf16x8*)(wg + k0 + 64 + (c0 + i) * 8);
            }
        }

        #pragma unroll
        for (int kk = 0; kk < 2; ++kk) {
            bf16x8 fa[4], fb[4];
            #pragma unroll
            for (int mi = 0; mi < 4; ++mi) {
                const int row = wm + mi * 16 + l16;
                fa[mi] = *(const bf16x8*)&Ash[row][SWE(kk * 4 + quad, row)];
            }
            #pragma unroll
            for (int ni = 0; ni < 4; ++ni) {
                const int row = wn + ni * 16 + l16;
                fb[ni] = *(const bf16x8*)&Bsh[row][SWE(kk * 4 + quad, row)];
            }
            #pragma unroll
            for (int mi = 0; mi < 4; ++mi)
                #pragma unroll
                for (int ni = 0; ni < 4; ++ni)
                    acc[mi][ni] = __builtin_amdgcn_mfma_f32_16x16x32_bf16(
                        fa[mi], fb[ni], acc[mi][ni], 0, 0, 0);
        }
    }

    if (!VM) {
        const float scale = (which == 0) ? 0.125f * 1.44269504088896340736f : 1.0f;
        __bf16* dst = (which == 0) ? Qo : Ko;
        // rows = e (W-dim), in-lane regs r span 4 consecutive e -> 4 consecutive d
        #pragma unroll
        for (int mi = 0; mi < 4; ++mi) {
            const int e0 = tn + wm + mi * 16 + quad * 4;
            const int h = e0 >> 6, d0 = e0 & 63;
            #pragma unroll
            for (int ni = 0; ni < 4; ++ni) {
                const int sf = tm + wn + ni * 16 + l16;
                const int b = sf >> 11, s = sf & (Ssz - 1);
                bf16x4 p;
                #pragma unroll
                for (int r = 0; r < 4; ++r) p[r] = (__bf16)(acc[mi][ni][r] * scale);
                *(bf16x4*)&dst[((((size_t)(b * Hsz + h) * Ssz + s)) << 6) + d0] = p;
            }
        }
    } else {
        // rows = s, in-lane regs r span 4 consecutive s -> V^T packed stores
        #pragma unroll
        for (int mi = 0; mi < 4; ++mi) {
            const int sf0 = tm + wm + mi * 16 + quad * 4;
            const int b = sf0 >> 11, s0 = sf0 & (Ssz - 1);
            #pragma unroll
            for (int ni = 0; ni < 4; ++ni) {
                const int e = tn + wn + ni * 16 + l16;
                const int h = e >> 6, d = e & 63;
                bf16x4 p;
                #pragma unroll
                for (int r = 0; r < 4; ++r) p[r] = (__bf16)acc[mi][ni][r];
                *(bf16x4*)&Vo[(((size_t)(b * Hsz + h) * DKsz + d) << 11) + s0] = p;
            }
        }
    }
}

// ---------------------------------------------------------------------------
// Flash attention, LDS-staged K/V (shared by 4 waves), XOR-swizzled, 128
// q-rows/block, qs=2 per wave. S computed TRANSPOSED (A=K-frag, B=Q-frag):
// a lane's 4 acc regs span 4 consecutive s for one q=l16, so P-writes pack
// into b64 (4/qs instead of 16 scalar b16) -- LDS-instr diet. PV uses
// swapped operands (A=V^T, B=P^T) => O^T in regs -> f32x4 stores; row-sums
// via ones-MFMA land per-lane (col=q=l16).
__global__ __launch_bounds__(256, 2) void attn_kernel(
    const __bf16* __restrict__ Q, const __bf16* __restrict__ K,
    const __bf16* __restrict__ VT, float* __restrict__ out)
{
    __shared__ __bf16 ks[64][64];        // K[s_local][dk], swizzled chunks
    __shared__ __bf16 vs[64][64];        // V^T[dk][s_local], swizzled chunks
    __shared__ __bf16 ps[4][16][64];     // per-wave P^T buffer [q][s], swizzled

    const int tid  = threadIdx.x;
    const int lane = tid & 63;
    const int wave = tid >> 6;
    const int quad = lane >> 4;
    const int l16  = lane & 15;

    const int bh = blockIdx.x;           // all q-blocks of a bh share an XCD L2
    const int qt = blockIdx.y;           // 128-row q tile
    const int b  = bh >> 3;
    const int h  = bh & 7;

    const __bf16* Qb = Q  + (size_t)bh * Ssz * DKsz;
    const __bf16* Kb = K  + (size_t)bh * Ssz * DKsz;
    const __bf16* Vb = VT + (size_t)bh * DKsz * Ssz;

    // Q fragments: lane l16 = q-local row, quad*8 = dk chunk
    bf16x8 qf[2][2];
    #pragma unroll
    for (int qs = 0; qs < 2; ++qs) {
        const __bf16* qrow = Qb + (size_t)(qt * 128 + wave * 32 + qs * 16 + l16) * DKsz;
        qf[qs][0] = *(const bf16x8*)(qrow + quad * 8);
        qf[qs][1] = *(const bf16x8*)(qrow + 32 + quad * 8);
    }

    bf16x8 ones;
    #pragma unroll
    for (int i = 0; i < 8; ++i) ones[i] = (__bf16)1.0f;

    f32x4 oacc[2][4];
    #pragma unroll
    for (int qs = 0; qs < 2; ++qs)
        #pragma unroll
        for (int i = 0; i < 4; ++i) oacc[qs][i] = (f32x4){0.f, 0.f, 0.f, 0.f};
    f32x4 lacc[2] = {(f32x4){0.f, 0.f, 0.f, 0.f}, (f32x4){0.f, 0.f, 0.f, 0.f}};

    const int srow = tid >> 2;           // 0..63
    const int c0   = tid & 3;            // chunks c0, c0+4

    bf16x8 pk0 = *(const bf16x8*)(Kb + (size_t)srow * DKsz + c0 * 8);
    bf16x8 pk1 = *(const bf16x8*)(Kb + (size_t)srow * DKsz + (c0 + 4) * 8);
    bf16x8 pv0 = *(const bf16x8*)(Vb + (size_t)srow * Ssz + c0 * 8);
    bf16x8 pv1 = *(const bf16x8*)(Vb + (size_t)srow * Ssz + (c0 + 4) * 8);

    for (int kb = 0; kb < Ssz; kb += 64) {
        __syncthreads();                 // previous tile fully consumed
        *(bf16x8*)&ks[srow][SWE(c0, srow)]     = pk0;
        *(bf16x8*)&ks[srow][SWE(c0 + 4, srow)] = pk1;
        *(bf16x8*)&vs[srow][SWE(c0, srow)]     = pv0;
        *(bf16x8*)&vs[srow][SWE(c0 + 4, srow)] = pv1;
        __syncthreads();

        if (kb + 64 < Ssz) {             // prefetch next K/V tile into regs
            pk0 = *(const bf16x8*)(Kb + (size_t)(kb + 64 + srow) * DKsz + c0 * 8);
            pk1 = *(const bf16x8*)(Kb + (size_t)(kb + 64 + srow) * DKsz + (c0 + 4) * 8);
            pv0 = *(const bf16x8*)(Vb + (size_t)srow * Ssz + kb + 64 + c0 * 8);
            pv1 = *(const bf16x8*)(Vb + (size_t)srow * Ssz + kb + 64 + (c0 + 4) * 8);
        }

        // read K and V tiles from LDS once into registers
        bf16x8 kf[2][4], vf[2][4];
        #pragma unroll
        for (int kk = 0; kk < 2; ++kk)
            #pragma unroll
            for (int ns = 0; ns < 4; ++ns) {
                const int row = ns * 16 + l16;
                kf[kk][ns] = *(const bf16x8*)&ks[row][SWE(kk * 4 + quad, row)];
                vf[kk][ns] = *(const bf16x8*)&vs[row][SWE(kk * 4 + quad, row)];
            }

        #pragma unroll
        for (int qs = 0; qs < 2; ++qs) {
            // S^T = K Q^T (C: row = s-local = ns*16+quad*4+r, col = q = l16)
            #pragma unroll
            for (int ns = 0; ns < 4; ++ns) {
                f32x4 st = (f32x4){0.f, 0.f, 0.f, 0.f};
                st = __builtin_amdgcn_mfma_f32_16x16x32_bf16(kf[0][ns], qf[qs][0], st, 0, 0, 0);
                st = __builtin_amdgcn_mfma_f32_16x16x32_bf16(kf[1][ns], qf[qs][1], st, 0, 0, 0);
                // P^T pack: 4 regs = 4 consecutive s for q=l16 -> one b64 write
                bf16x4 pp;
                #pragma unroll
                for (int r = 0; r < 4; ++r)
                    pp[r] = (__bf16)__builtin_amdgcn_exp2f(st[r]);
                const int c = ns * 2 + (quad >> 1);       // 16B chunk of [q][s] row
                *(bf16x4*)&ps[wave][l16][((c ^ (l16 & 7)) << 3) + ((quad & 1) << 2)] = pp;
            }
            bf16x8 af0 = *(const bf16x8*)&ps[wave][l16][SWE(quad, l16)];
            bf16x8 af1 = *(const bf16x8*)&ps[wave][l16][SWE(4 + quad, l16)];
            // O^T += V^T P^T : rows=d (in-lane regs), cols=q (l16)
            #pragma unroll
            for (int ns = 0; ns < 4; ++ns) {
                oacc[qs][ns] = __builtin_amdgcn_mfma_f32_16x16x32_bf16(vf[0][ns], af0, oacc[qs][ns], 0, 0, 0);
                oacc[qs][ns] = __builtin_amdgcn_mfma_f32_16x16x32_bf16(vf[1][ns], af1, oacc[qs][ns], 0, 0, 0);
            }
            lacc[qs] = __builtin_amdgcn_mfma_f32_16x16x32_bf16(ones, af0, lacc[qs], 0, 0, 0);
            lacc[qs] = __builtin_amdgcn_mfma_f32_16x16x32_bf16(ones, af1, lacc[qs], 0, 0, 0);
        }
    }

    // epilogue: per-lane row-sum (col=q=l16), f32x4 stores along d
    #pragma unroll
    for (int qs = 0; qs < 2; ++qs) {
        const float linv = 1.f / (lacc[qs][0] + 1e-8f);
        const int q = qt * 128 + wave * 32 + qs * 16 + l16;
        float* obase = out + ((size_t)b * Ssz + q) * Dsz + h * DKsz;
        #pragma unroll
        for (int ns = 0; ns < 4; ++ns) {
            f32x4 o = oacc[qs][ns] * linv;
            *(f32x4*)(obase + ns * 16 + quad * 4) = o;
        }
    }
}

extern "C" void kernel_launch(void* const* d_in, const int* in_sizes, int n_in,
                              void* d_out, int out_size, void* d_ws, size_t ws_size,
                              hipStream_t stream) {
    const float* x  = (const float*)d_in[0];
    const float* Wq = (const float*)d_in[1];
    const float* Wk = (const float*)d_in[2];
    const float* Wv = (const float*)d_in[3];
    float* out = (float*)d_out;

    const size_t per = (size_t)Bsz * Hsz * Ssz * DKsz;  // 4,194,304 elems
    __bf16* Qw  = (__bf16*)d_ws;
    __bf16* Kw  = Qw + per;
    __bf16* VTw = Kw + per;
    __bf16* xb  = VTw + per;
    __bf16* Wb  = xb + per;                              // 786,432 elems

    cvt_kernel<<<4864, 256, 0, stream>>>(x, Wq, Wk, Wv, xb, Wb);
    qkv_kernel<<<dim3((Bsz * Ssz) / 128, Dsz / 128, 3), 256, 0, stream>>>(
        xb, Wb, Qw, Kw, VTw);
    attn_kernel<<<dim3(Bsz * Hsz, Ssz / 128), 256, 0, stream>>>(Qw, Kw, VTw, out);
}

// Round 8
// 138.359 us; speedup vs baseline: 1.5406x; 1.0088x over previous
//
#include <hip/hip_runtime.h>
#include <hip/hip_bf16.h>

#define Bsz 4
#define Ssz 2048
#define Dsz 512
#define Hsz 8
#define DKsz 64

typedef __bf16 bf16x8 __attribute__((ext_vector_type(8)));
typedef __bf16 bf16x4 __attribute__((ext_vector_type(4)));
typedef float f32x4 __attribute__((ext_vector_type(4)));

// chunk-swizzled element offset: 16B chunk c of a 64-elem (128B) row, XOR row&7
#define SWE(c, row) ((((c) ^ ((row) & 7)) * 8))

// ---------------------------------------------------------------------------
// cvt: x (4.19M fp32) + Wq|Wk|Wv (3 x 262144 fp32) -> bf16 in ws.
__global__ __launch_bounds__(256) void cvt_kernel(
    const float* __restrict__ x, const float* __restrict__ Wq,
    const float* __restrict__ Wk, const float* __restrict__ Wv,
    __bf16* __restrict__ xb, __bf16* __restrict__ Wb)
{
    const int i = blockIdx.x * 256 + threadIdx.x;   // float4 index
    const int XN4 = (Bsz * Ssz * Dsz) / 4;          // 1,048,576
    const float* src;
    __bf16* dst;
    int off;
    if (i < XN4) {
        src = x; dst = xb; off = i;
    } else {
        int j = i - XN4;                             // 0 .. 196607
        int w = j >> 16;                             // 0,1,2
        off = j & 65535;
        src = (w == 0) ? Wq : (w == 1) ? Wk : Wv;
        dst = Wb + (size_t)w * (Dsz * Dsz);
    }
    float4 v = ((const float4*)src)[off];
    __bf16 o[4] = {(__bf16)v.x, (__bf16)v.y, (__bf16)v.z, (__bf16)v.w};
    *(uint2*)(dst + (size_t)off * 4) = *(uint2*)o;
}

// ---------------------------------------------------------------------------
// Fused qkv projection. 128x128 tile, swizzled LDS, reg prefetch, packed 8B
// stores. Staging is LINE-COALESCED: per global_load_dwordx4, 8 lanes cover
// one full 128-B cache line (lane L -> row L>>3, byte (L&7)*16), 8 lines per
// instruction -- vs the old 64 scattered 16-B segments.
// which<2 (Q/K): C = W-tile x x-tile -> rows=e (in-lane), cols=s.
// which==2 (V) : C = x-tile x W-tile -> rows=s (in-lane), cols=e -> V^T.
__global__ __launch_bounds__(256, 3) void qkv_kernel(
    const __bf16* __restrict__ xb, const __bf16* __restrict__ Wb,
    __bf16* __restrict__ Qo, __bf16* __restrict__ Ko, __bf16* __restrict__ Vo)
{
    __shared__ __bf16 xs[128][64];
    __shared__ __bf16 wsh[128][64];

    const int tid  = threadIdx.x;
    const int lane = tid & 63;
    const int wave = tid >> 6;
    const int quad = lane >> 4;
    const int l16  = lane & 15;
    const int wm   = (wave & 1) * 64;
    const int wn   = (wave >> 1) * 64;

    const int tm = blockIdx.x * 128;      // x-row tile
    const int tn = blockIdx.y * 128;      // W-row tile
    const int which = blockIdx.z;         // 0=Q 1=K 2=V  (grid: ids ≡ tm-tile
    const bool VM = (which == 2);         //  mod 8 -> x-tile sharers same XCD)
    const __bf16* W = Wb + (size_t)which * (Dsz * Dsz);

    const int srow = tid >> 3;            // 0..31 (+32i covers 128 rows)
    const int sc   = tid & 7;             // 16B chunk within the 128B row
    const int swz  = SWE(sc, srow);       // (srow+32i)&7 == srow&7: i-invariant

    const __bf16* xg = xb + (size_t)(tm + srow) * Dsz + sc * 8;
    const __bf16* wg = W  + (size_t)(tn + srow) * Dsz + sc * 8;

    bf16x8 px[4], pw[4];
    #pragma unroll
    for (int i = 0; i < 4; ++i) {
        px[i] = *(const bf16x8*)(xg + (size_t)(32 * i) * Dsz);
        pw[i] = *(const bf16x8*)(wg + (size_t)(32 * i) * Dsz);
    }

    f32x4 acc[4][4];
    #pragma unroll
    for (int i = 0; i < 4; ++i)
        #pragma unroll
        for (int j = 0; j < 4; ++j) acc[i][j] = (f32x4){0.f, 0.f, 0.f, 0.f};

    const __bf16 (*Ash)[64] = VM ? xs : wsh;
    const __bf16 (*Bsh)[64] = VM ? wsh : xs;

    for (int k0 = 0; k0 < Dsz; k0 += 64) {
        __syncthreads();
        #pragma unroll
        for (int i = 0; i < 4; ++i) {
            *(bf16x8*)&xs[srow + 32 * i][swz]  = px[i];
            *(bf16x8*)&wsh[srow + 32 * i][swz] = pw[i];
        }
        __syncthreads();
        if (k0 + 64 < Dsz) {
            #pragma unroll
            for (int i = 0; i < 4; ++i) {
                px[i] = *(const bf16x8*)(xg + (size_t)(32 * i) * Dsz + k0 + 64);
                pw[i] = *(const bf16x8*)(wg + (size_t)(32 * i) * Dsz + k0 + 64);
            }
        }

        #pragma unroll
        for (int kk = 0; kk < 2; ++kk) {
            bf16x8 fa[4], fb[4];
            #pragma unroll
            for (int mi = 0; mi < 4; ++mi) {
                const int row = wm + mi * 16 + l16;
                fa[mi] = *(const bf16x8*)&Ash[row][SWE(kk * 4 + quad, row)];
            }
            #pragma unroll
            for (int ni = 0; ni < 4; ++ni) {
                const int row = wn + ni * 16 + l16;
                fb[ni] = *(const bf16x8*)&Bsh[row][SWE(kk * 4 + quad, row)];
            }
            #pragma unroll
            for (int mi = 0; mi < 4; ++mi)
                #pragma unroll
                for (int ni = 0; ni < 4; ++ni)
                    acc[mi][ni] = __builtin_amdgcn_mfma_f32_16x16x32_bf16(
                        fa[mi], fb[ni], acc[mi][ni], 0, 0, 0);
        }
    }

    if (!VM) {
        const float scale = (which == 0) ? 0.125f * 1.44269504088896340736f : 1.0f;
        __bf16* dst = (which == 0) ? Qo : Ko;
        // rows = e (W-dim), in-lane regs r span 4 consecutive e -> 4 consecutive d
        #pragma unroll
        for (int mi = 0; mi < 4; ++mi) {
            const int e0 = tn + wm + mi * 16 + quad * 4;
            const int h = e0 >> 6, d0 = e0 & 63;
            #pragma unroll
            for (int ni = 0; ni < 4; ++ni) {
                const int sf = tm + wn + ni * 16 + l16;
                const int b = sf >> 11, s = sf & (Ssz - 1);
                bf16x4 p;
                #pragma unroll
                for (int r = 0; r < 4; ++r) p[r] = (__bf16)(acc[mi][ni][r] * scale);
                *(bf16x4*)&dst[((((size_t)(b * Hsz + h) * Ssz + s)) << 6) + d0] = p;
            }
        }
    } else {
        // rows = s, in-lane regs r span 4 consecutive s -> V^T packed stores
        #pragma unroll
        for (int mi = 0; mi < 4; ++mi) {
            const int sf0 = tm + wm + mi * 16 + quad * 4;
            const int b = sf0 >> 11, s0 = sf0 & (Ssz - 1);
            #pragma unroll
            for (int ni = 0; ni < 4; ++ni) {
                const int e = tn + wn + ni * 16 + l16;
                const int h = e >> 6, d = e & 63;
                bf16x4 p;
                #pragma unroll
                for (int r = 0; r < 4; ++r) p[r] = (__bf16)acc[mi][ni][r];
                *(bf16x4*)&Vo[(((size_t)(b * Hsz + h) * DKsz + d) << 11) + s0] = p;
            }
        }
    }
}

// ---------------------------------------------------------------------------
// Flash attention, LDS-staged K/V, XOR-swizzled, 128 q-rows/block, qs=2.
// S computed transposed (A=K,B=Q) -> P^T packs to b64 LDS writes; PV swapped
// (A=V^T, B=P^T) -> O^T regs -> f32x4 stores; row-sums via ones-MFMA.
// Staging line-coalesced like qkv (8 lanes per 128-B line per instruction).
__global__ __launch_bounds__(256, 2) void attn_kernel(
    const __bf16* __restrict__ Q, const __bf16* __restrict__ K,
    const __bf16* __restrict__ VT, float* __restrict__ out)
{
    __shared__ __bf16 ks[64][64];        // K[s_local][dk], swizzled chunks
    __shared__ __bf16 vs[64][64];        // V^T[dk][s_local], swizzled chunks
    __shared__ __bf16 ps[4][16][64];     // per-wave P^T buffer [q][s], swizzled

    const int tid  = threadIdx.x;
    const int lane = tid & 63;
    const int wave = tid >> 6;
    const int quad = lane >> 4;
    const int l16  = lane & 15;

    const int bh = blockIdx.x;           // all q-blocks of a bh share an XCD L2
    const int qt = blockIdx.y;           // 128-row q tile
    const int b  = bh >> 3;
    const int h  = bh & 7;

    const __bf16* Qb = Q  + (size_t)bh * Ssz * DKsz;
    const __bf16* Kb = K  + (size_t)bh * Ssz * DKsz;
    const __bf16* Vb = VT + (size_t)bh * DKsz * Ssz;

    // Q fragments: lane l16 = q-local row, quad*8 = dk chunk
    bf16x8 qf[2][2];
    #pragma unroll
    for (int qs = 0; qs < 2; ++qs) {
        const __bf16* qrow = Qb + (size_t)(qt * 128 + wave * 32 + qs * 16 + l16) * DKsz;
        qf[qs][0] = *(const bf16x8*)(qrow + quad * 8);
        qf[qs][1] = *(const bf16x8*)(qrow + 32 + quad * 8);
    }

    bf16x8 ones;
    #pragma unroll
    for (int i = 0; i < 8; ++i) ones[i] = (__bf16)1.0f;

    f32x4 oacc[2][4];
    #pragma unroll
    for (int qs = 0; qs < 2; ++qs)
        #pragma unroll
        for (int i = 0; i < 4; ++i) oacc[qs][i] = (f32x4){0.f, 0.f, 0.f, 0.f};
    f32x4 lacc[2] = {(f32x4){0.f, 0.f, 0.f, 0.f}, (f32x4){0.f, 0.f, 0.f, 0.f}};

    const int srow = tid >> 3;           // 0..31 (+32 covers 64 rows)
    const int sc   = tid & 7;            // 16B chunk within the 128B row
    const int swz  = SWE(sc, srow);      // (srow+32)&7 == srow&7

    const __bf16* kg = Kb + (size_t)srow * DKsz + sc * 8;   // K rows = 128B
    const __bf16* vg = Vb + (size_t)srow * Ssz + sc * 8;    // V^T kb-slice

    bf16x8 pk0 = *(const bf16x8*)(kg);
    bf16x8 pk1 = *(const bf16x8*)(kg + (size_t)32 * DKsz);
    bf16x8 pv0 = *(const bf16x8*)(vg);
    bf16x8 pv1 = *(const bf16x8*)(vg + (size_t)32 * Ssz);

    for (int kb = 0; kb < Ssz; kb += 64) {
        __syncthreads();                 // previous tile fully consumed
        *(bf16x8*)&ks[srow][swz]      = pk0;
        *(bf16x8*)&ks[srow + 32][swz] = pk1;
        *(bf16x8*)&vs[srow][swz]      = pv0;
        *(bf16x8*)&vs[srow + 32][swz] = pv1;
        __syncthreads();

        if (kb + 64 < Ssz) {             // prefetch next K/V tile into regs
            pk0 = *(const bf16x8*)(kg + (size_t)(kb + 64) * DKsz);
            pk1 = *(const bf16x8*)(kg + (size_t)(kb + 96) * DKsz);
            pv0 = *(const bf16x8*)(vg + kb + 64);
            pv1 = *(const bf16x8*)(vg + (size_t)32 * Ssz + kb + 64);
        }

        // read K and V tiles from LDS once into registers
        bf16x8 kf[2][4], vf[2][4];
        #pragma unroll
        for (int kk = 0; kk < 2; ++kk)
            #pragma unroll
            for (int ns = 0; ns < 4; ++ns) {
                const int row = ns * 16 + l16;
                kf[kk][ns] = *(const bf16x8*)&ks[row][SWE(kk * 4 + quad, row)];
                vf[kk][ns] = *(const bf16x8*)&vs[row][SWE(kk * 4 + quad, row)];
            }

        #pragma unroll
        for (int qs = 0; qs < 2; ++qs) {
            // S^T = K Q^T (C: row = s-local = ns*16+quad*4+r, col = q = l16)
            #pragma unroll
            for (int ns = 0; ns < 4; ++ns) {
                f32x4 st = (f32x4){0.f, 0.f, 0.f, 0.f};
                st = __builtin_amdgcn_mfma_f32_16x16x32_bf16(kf[0][ns], qf[qs][0], st, 0, 0, 0);
                st = __builtin_amdgcn_mfma_f32_16x16x32_bf16(kf[1][ns], qf[qs][1], st, 0, 0, 0);
                // P^T pack: 4 regs = 4 consecutive s for q=l16 -> one b64 write
                bf16x4 pp;
                #pragma unroll
                for (int r = 0; r < 4; ++r)
                    pp[r] = (__bf16)__builtin_amdgcn_exp2f(st[r]);
                const int c = ns * 2 + (quad >> 1);       // 16B chunk of [q][s] row
                *(bf16x4*)&ps[wave][l16][((c ^ (l16 & 7)) << 3) + ((quad & 1) << 2)] = pp;
            }
            bf16x8 af0 = *(const bf16x8*)&ps[wave][l16][SWE(quad, l16)];
            bf16x8 af1 = *(const bf16x8*)&ps[wave][l16][SWE(4 + quad, l16)];
            // O^T += V^T P^T : rows=d (in-lane regs), cols=q (l16)
            #pragma unroll
            for (int ns = 0; ns < 4; ++ns) {
                oacc[qs][ns] = __builtin_amdgcn_mfma_f32_16x16x32_bf16(vf[0][ns], af0, oacc[qs][ns], 0, 0, 0);
                oacc[qs][ns] = __builtin_amdgcn_mfma_f32_16x16x32_bf16(vf[1][ns], af1, oacc[qs][ns], 0, 0, 0);
            }
            lacc[qs] = __builtin_amdgcn_mfma_f32_16x16x32_bf16(ones, af0, lacc[qs], 0, 0, 0);
            lacc[qs] = __builtin_amdgcn_mfma_f32_16x16x32_bf16(ones, af1, lacc[qs], 0, 0, 0);
        }
    }

    // epilogue: per-lane row-sum (col=q=l16), f32x4 stores along d
    #pragma unroll
    for (int qs = 0; qs < 2; ++qs) {
        const float linv = 1.f / (lacc[qs][0] + 1e-8f);
        const int q = qt * 128 + wave * 32 + qs * 16 + l16;
        float* obase = out + ((size_t)b * Ssz + q) * Dsz + h * DKsz;
        #pragma unroll
        for (int ns = 0; ns < 4; ++ns) {
            f32x4 o = oacc[qs][ns] * linv;
            *(f32x4*)(obase + ns * 16 + quad * 4) = o;
        }
    }
}

extern "C" void kernel_launch(void* const* d_in, const int* in_sizes, int n_in,
                              void* d_out, int out_size, void* d_ws, size_t ws_size,
                              hipStream_t stream) {
    const float* x  = (const float*)d_in[0];
    const float* Wq = (const float*)d_in[1];
    const float* Wk = (const float*)d_in[2];
    const float* Wv = (const float*)d_in[3];
    float* out = (float*)d_out;

    const size_t per = (size_t)Bsz * Hsz * Ssz * DKsz;  // 4,194,304 elems
    __bf16* Qw  = (__bf16*)d_ws;
    __bf16* Kw  = Qw + per;
    __bf16* VTw = Kw + per;
    __bf16* xb  = VTw + per;
    __bf16* Wb  = xb + per;                              // 786,432 elems

    cvt_kernel<<<4864, 256, 0, stream>>>(x, Wq, Wk, Wv, xb, Wb);
    qkv_kernel<<<dim3((Bsz * Ssz) / 128, Dsz / 128, 3), 256, 0, stream>>>(
        xb, Wb, Qw, Kw, VTw);
    attn_kernel<<<dim3(Bsz * Hsz, Ssz / 128), 256, 0, stream>>>(Qw, Kw, VTw, out);
}

// Round 9
// 137.241 us; speedup vs baseline: 1.5531x; 1.0081x over previous
//
#include <hip/hip_runtime.h>
#include <hip/hip_bf16.h>

#define Bsz 4
#define Ssz 2048
#define Dsz 512
#define Hsz 8
#define DKsz 64

typedef __bf16 bf16x8 __attribute__((ext_vector_type(8)));
typedef __bf16 bf16x4 __attribute__((ext_vector_type(4)));
typedef float f32x4 __attribute__((ext_vector_type(4)));

// chunk-swizzled element offset: 16B chunk c of a 64-elem (128B) row, XOR row&7
#define SWE(c, row) ((((c) ^ ((row) & 7)) * 8))

// ---------------------------------------------------------------------------
// cvt: x (4.19M fp32) + Wq|Wk|Wv (3 x 262144 fp32) -> bf16 in ws.
__global__ __launch_bounds__(256) void cvt_kernel(
    const float* __restrict__ x, const float* __restrict__ Wq,
    const float* __restrict__ Wk, const float* __restrict__ Wv,
    __bf16* __restrict__ xb, __bf16* __restrict__ Wb)
{
    const int i = blockIdx.x * 256 + threadIdx.x;   // float4 index
    const int XN4 = (Bsz * Ssz * Dsz) / 4;          // 1,048,576
    const float* src;
    __bf16* dst;
    int off;
    if (i < XN4) {
        src = x; dst = xb; off = i;
    } else {
        int j = i - XN4;                             // 0 .. 196607
        int w = j >> 16;                             // 0,1,2
        off = j & 65535;
        src = (w == 0) ? Wq : (w == 1) ? Wk : Wv;
        dst = Wb + (size_t)w * (Dsz * Dsz);
    }
    float4 v = ((const float4*)src)[off];
    __bf16 o[4] = {(__bf16)v.x, (__bf16)v.y, (__bf16)v.z, (__bf16)v.w};
    *(uint2*)(dst + (size_t)off * 4) = *(uint2*)o;
}

// ---------------------------------------------------------------------------
// Fused qkv projection, L2-LOCALITY SWIZZLED grid (1-D, 768 blocks).
// XCD = lin&7 (dispatch round-robin); per XCD, 12 time-adjacent blocks share
// ONE x-tile (tm = (lin>>3)/12*8+xcd) and sweep all 12 (tn,which) W-tiles ->
// concurrent per-XCD footprint ~3 x-tiles + 1.5 MB W << 4 MB L2 (was ~24 MB,
// thrashing -> all 196 MB staged at HBM rate).
// 128x128 tile, swizzled LDS, reg prefetch, packed 8B stores.
// which<2 (Q/K): C = W-tile x x-tile -> rows=e (in-lane), cols=s.
// which==2 (V) : C = x-tile x W-tile -> rows=s (in-lane), cols=e -> V^T.
__global__ __launch_bounds__(256, 3) void qkv_kernel(
    const __bf16* __restrict__ xb, const __bf16* __restrict__ Wb,
    __bf16* __restrict__ Qo, __bf16* __restrict__ Ko, __bf16* __restrict__ Vo)
{
    __shared__ __bf16 xs[128][64];
    __shared__ __bf16 wsh[128][64];

    const int tid  = threadIdx.x;
    const int lane = tid & 63;
    const int wave = tid >> 6;
    const int quad = lane >> 4;
    const int l16  = lane & 15;
    const int wm   = (wave & 1) * 64;
    const int wn   = (wave >> 1) * 64;

    const int lin = blockIdx.x;
    const int xcd = lin & 7;
    const int idx = lin >> 3;             // 0..95
    const int tnw = idx % 12;             // fast per XCD: sweeps (tn, which)
    const int tmh = idx / 12;             // slow: x-tile group
    const int tm  = (tmh * 8 + xcd) * 128;
    const int tn  = (tnw & 3) * 128;
    const int which = tnw >> 2;           // 0=Q 1=K 2=V
    const bool VM = (which == 2);
    const __bf16* W = Wb + (size_t)which * (Dsz * Dsz);

    const int srow = tid >> 3;            // 0..31 (+32i covers 128 rows)
    const int sc   = tid & 7;             // 16B chunk within the 128B row
    const int swz  = SWE(sc, srow);       // (srow+32i)&7 == srow&7: i-invariant

    const __bf16* xg = xb + (size_t)(tm + srow) * Dsz + sc * 8;
    const __bf16* wg = W  + (size_t)(tn + srow) * Dsz + sc * 8;

    bf16x8 px[4], pw[4];
    #pragma unroll
    for (int i = 0; i < 4; ++i) {
        px[i] = *(const bf16x8*)(xg + (size_t)(32 * i) * Dsz);
        pw[i] = *(const bf16x8*)(wg + (size_t)(32 * i) * Dsz);
    }

    f32x4 acc[4][4];
    #pragma unroll
    for (int i = 0; i < 4; ++i)
        #pragma unroll
        for (int j = 0; j < 4; ++j) acc[i][j] = (f32x4){0.f, 0.f, 0.f, 0.f};

    const __bf16 (*Ash)[64] = VM ? xs : wsh;
    const __bf16 (*Bsh)[64] = VM ? wsh : xs;

    for (int k0 = 0; k0 < Dsz; k0 += 64) {
        __syncthreads();
        #pragma unroll
        for (int i = 0; i < 4; ++i) {
            *(bf16x8*)&xs[srow + 32 * i][swz]  = px[i];
            *(bf16x8*)&wsh[srow + 32 * i][swz] = pw[i];
        }
        __syncthreads();
        if (k0 + 64 < Dsz) {
            #pragma unroll
            for (int i = 0; i < 4; ++i) {
                px[i] = *(const bf16x8*)(xg + (size_t)(32 * i) * Dsz + k0 + 64);
                pw[i] = *(const bf16x8*)(wg + (size_t)(32 * i) * Dsz + k0 + 64);
            }
        }

        #pragma unroll
        for (int kk = 0; kk < 2; ++kk) {
            bf16x8 fa[4], fb[4];
            #pragma unroll
            for (int mi = 0; mi < 4; ++mi) {
                const int row = wm + mi * 16 + l16;
                fa[mi] = *(const bf16x8*)&Ash[row][SWE(kk * 4 + quad, row)];
            }
            #pragma unroll
            for (int ni = 0; ni < 4; ++ni) {
                const int row = wn + ni * 16 + l16;
                fb[ni] = *(const bf16x8*)&Bsh[row][SWE(kk * 4 + quad, row)];
            }
            #pragma unroll
            for (int mi = 0; mi < 4; ++mi)
                #pragma unroll
                for (int ni = 0; ni < 4; ++ni)
                    acc[mi][ni] = __builtin_amdgcn_mfma_f32_16x16x32_bf16(
                        fa[mi], fb[ni], acc[mi][ni], 0, 0, 0);
        }
    }

    if (!VM) {
        const float scale = (which == 0) ? 0.125f * 1.44269504088896340736f : 1.0f;
        __bf16* dst = (which == 0) ? Qo : Ko;
        // rows = e (W-dim), in-lane regs r span 4 consecutive e -> 4 consecutive d
        #pragma unroll
        for (int mi = 0; mi < 4; ++mi) {
            const int e0 = tn + wm + mi * 16 + quad * 4;
            const int h = e0 >> 6, d0 = e0 & 63;
            #pragma unroll
            for (int ni = 0; ni < 4; ++ni) {
                const int sf = tm + wn + ni * 16 + l16;
                const int b = sf >> 11, s = sf & (Ssz - 1);
                bf16x4 p;
                #pragma unroll
                for (int r = 0; r < 4; ++r) p[r] = (__bf16)(acc[mi][ni][r] * scale);
                *(bf16x4*)&dst[((((size_t)(b * Hsz + h) * Ssz + s)) << 6) + d0] = p;
            }
        }
    } else {
        // rows = s, in-lane regs r span 4 consecutive s -> V^T packed stores
        #pragma unroll
        for (int mi = 0; mi < 4; ++mi) {
            const int sf0 = tm + wm + mi * 16 + quad * 4;
            const int b = sf0 >> 11, s0 = sf0 & (Ssz - 1);
            #pragma unroll
            for (int ni = 0; ni < 4; ++ni) {
                const int e = tn + wn + ni * 16 + l16;
                const int h = e >> 6, d = e & 63;
                bf16x4 p;
                #pragma unroll
                for (int r = 0; r < 4; ++r) p[r] = (__bf16)acc[mi][ni][r];
                *(bf16x4*)&Vo[(((size_t)(b * Hsz + h) * DKsz + d) << 11) + s0] = p;
            }
        }
    }
}

// ---------------------------------------------------------------------------
// Flash attention, LDS-staged K/V, XOR-swizzled, 128 q-rows/block, qs=2.
// S computed transposed (A=K,B=Q) -> P^T packs to b64 LDS writes; PV swapped
// (A=V^T, B=P^T) -> O^T regs -> f32x4 stores; row-sums via ones-MFMA.
// Staging line-coalesced (8 lanes per 128-B line per instruction).
__global__ __launch_bounds__(256, 2) void attn_kernel(
    const __bf16* __restrict__ Q, const __bf16* __restrict__ K,
    const __bf16* __restrict__ VT, float* __restrict__ out)
{
    __shared__ __bf16 ks[64][64];        // K[s_local][dk], swizzled chunks
    __shared__ __bf16 vs[64][64];        // V^T[dk][s_local], swizzled chunks
    __shared__ __bf16 ps[4][16][64];     // per-wave P^T buffer [q][s], swizzled

    const int tid  = threadIdx.x;
    const int lane = tid & 63;
    const int wave = tid >> 6;
    const int quad = lane >> 4;
    const int l16  = lane & 15;

    const int bh = blockIdx.x;           // all q-blocks of a bh share an XCD L2
    const int qt = blockIdx.y;           // 128-row q tile
    const int b  = bh >> 3;
    const int h  = bh & 7;

    const __bf16* Qb = Q  + (size_t)bh * Ssz * DKsz;
    const __bf16* Kb = K  + (size_t)bh * Ssz * DKsz;
    const __bf16* Vb = VT + (size_t)bh * DKsz * Ssz;

    // Q fragments: lane l16 = q-local row, quad*8 = dk chunk
    bf16x8 qf[2][2];
    #pragma unroll
    for (int qs = 0; qs < 2; ++qs) {
        const __bf16* qrow = Qb + (size_t)(qt * 128 + wave * 32 + qs * 16 + l16) * DKsz;
        qf[qs][0] = *(const bf16x8*)(qrow + quad * 8);
        qf[qs][1] = *(const bf16x8*)(qrow + 32 + quad * 8);
    }

    bf16x8 ones;
    #pragma unroll
    for (int i = 0; i < 8; ++i) ones[i] = (__bf16)1.0f;

    f32x4 oacc[2][4];
    #pragma unroll
    for (int qs = 0; qs < 2; ++qs)
        #pragma unroll
        for (int i = 0; i < 4; ++i) oacc[qs][i] = (f32x4){0.f, 0.f, 0.f, 0.f};
    f32x4 lacc[2] = {(f32x4){0.f, 0.f, 0.f, 0.f}, (f32x4){0.f, 0.f, 0.f, 0.f}};

    const int srow = tid >> 3;           // 0..31 (+32 covers 64 rows)
    const int sc   = tid & 7;            // 16B chunk within the 128B row
    const int swz  = SWE(sc, srow);      // (srow+32)&7 == srow&7

    const __bf16* kg = Kb + (size_t)srow * DKsz + sc * 8;   // K rows = 128B
    const __bf16* vg = Vb + (size_t)srow * Ssz + sc * 8;    // V^T kb-slice

    bf16x8 pk0 = *(const bf16x8*)(kg);
    bf16x8 pk1 = *(const bf16x8*)(kg + (size_t)32 * DKsz);
    bf16x8 pv0 = *(const bf16x8*)(vg);
    bf16x8 pv1 = *(const bf16x8*)(vg + (size_t)32 * Ssz);

    for (int kb = 0; kb < Ssz; kb += 64) {
        __syncthreads();                 // previous tile fully consumed
        *(bf16x8*)&ks[srow][swz]      = pk0;
        *(bf16x8*)&ks[srow + 32][swz] = pk1;
        *(bf16x8*)&vs[srow][swz]      = pv0;
        *(bf16x8*)&vs[srow + 32][swz] = pv1;
        __syncthreads();

        if (kb + 64 < Ssz) {             // prefetch next K/V tile into regs
            pk0 = *(const bf16x8*)(kg + (size_t)(kb + 64) * DKsz);
            pk1 = *(const bf16x8*)(kg + (size_t)(kb + 96) * DKsz);
            pv0 = *(const bf16x8*)(vg + kb + 64);
            pv1 = *(const bf16x8*)(vg + (size_t)32 * Ssz + kb + 64);
        }

        // read K and V tiles from LDS once into registers
        bf16x8 kf[2][4], vf[2][4];
        #pragma unroll
        for (int kk = 0; kk < 2; ++kk)
            #pragma unroll
            for (int ns = 0; ns < 4; ++ns) {
                const int row = ns * 16 + l16;
                kf[kk][ns] = *(const bf16x8*)&ks[row][SWE(kk * 4 + quad, row)];
                vf[kk][ns] = *(const bf16x8*)&vs[row][SWE(kk * 4 + quad, row)];
            }

        #pragma unroll
        for (int qs = 0; qs < 2; ++qs) {
            // S^T = K Q^T (C: row = s-local = ns*16+quad*4+r, col = q = l16)
            #pragma unroll
            for (int ns = 0; ns < 4; ++ns) {
                f32x4 st = (f32x4){0.f, 0.f, 0.f, 0.f};
                st = __builtin_amdgcn_mfma_f32_16x16x32_bf16(kf[0][ns], qf[qs][0], st, 0, 0, 0);
                st = __builtin_amdgcn_mfma_f32_16x16x32_bf16(kf[1][ns], qf[qs][1], st, 0, 0, 0);
                // P^T pack: 4 regs = 4 consecutive s for q=l16 -> one b64 write
                bf16x4 pp;
                #pragma unroll
                for (int r = 0; r < 4; ++r)
                    pp[r] = (__bf16)__builtin_amdgcn_exp2f(st[r]);
                const int c = ns * 2 + (quad >> 1);       // 16B chunk of [q][s] row
                *(bf16x4*)&ps[wave][l16][((c ^ (l16 & 7)) << 3) + ((quad & 1) << 2)] = pp;
            }
            bf16x8 af0 = *(const bf16x8*)&ps[wave][l16][SWE(quad, l16)];
            bf16x8 af1 = *(const bf16x8*)&ps[wave][l16][SWE(4 + quad, l16)];
            // O^T += V^T P^T : rows=d (in-lane regs), cols=q (l16)
            #pragma unroll
            for (int ns = 0; ns < 4; ++ns) {
                oacc[qs][ns] = __builtin_amdgcn_mfma_f32_16x16x32_bf16(vf[0][ns], af0, oacc[qs][ns], 0, 0, 0);
                oacc[qs][ns] = __builtin_amdgcn_mfma_f32_16x16x32_bf16(vf[1][ns], af1, oacc[qs][ns], 0, 0, 0);
            }
            lacc[qs] = __builtin_amdgcn_mfma_f32_16x16x32_bf16(ones, af0, lacc[qs], 0, 0, 0);
            lacc[qs] = __builtin_amdgcn_mfma_f32_16x16x32_bf16(ones, af1, lacc[qs], 0, 0, 0);
        }
    }

    // epilogue: per-lane row-sum (col=q=l16), f32x4 stores along d
    #pragma unroll
    for (int qs = 0; qs < 2; ++qs) {
        const float linv = 1.f / (lacc[qs][0] + 1e-8f);
        const int q = qt * 128 + wave * 32 + qs * 16 + l16;
        float* obase = out + ((size_t)b * Ssz + q) * Dsz + h * DKsz;
        #pragma unroll
        for (int ns = 0; ns < 4; ++ns) {
            f32x4 o = oacc[qs][ns] * linv;
            *(f32x4*)(obase + ns * 16 + quad * 4) = o;
        }
    }
}

extern "C" void kernel_launch(void* const* d_in, const int* in_sizes, int n_in,
                              void* d_out, int out_size, void* d_ws, size_t ws_size,
                              hipStream_t stream) {
    const float* x  = (const float*)d_in[0];
    const float* Wq = (const float*)d_in[1];
    const float* Wk = (const float*)d_in[2];
    const float* Wv = (const float*)d_in[3];
    float* out = (float*)d_out;

    const size_t per = (size_t)Bsz * Hsz * Ssz * DKsz;  // 4,194,304 elems
    __bf16* Qw  = (__bf16*)d_ws;
    __bf16* Kw  = Qw + per;
    __bf16* VTw = Kw + per;
    __bf16* xb  = VTw + per;
    __bf16* Wb  = xb + per;                              // 786,432 elems

    cvt_kernel<<<4864, 256, 0, stream>>>(x, Wq, Wk, Wv, xb, Wb);
    qkv_kernel<<<768, 256, 0, stream>>>(xb, Wb, Qw, Kw, VTw);
    attn_kernel<<<dim3(Bsz * Hsz, Ssz / 128), 256, 0, stream>>>(Qw, Kw, VTw, out);
}